// Round 9
// baseline (209.076 us; speedup 1.0000x reference)
//
#include <hip/hip_runtime.h>

// Attention_53798760350071: B=4 N=2048 D=768 H=12 HD=64, SCALE=0.125
// Dtype-agnostic (inline 64-sample ballot detection); bf16 MFMA pipeline.
// d_out = [proj_out (4,2048,768)] ++ [q_attn (4,12,2048)].
// Workspace: 68,026,816 bytes (fused q_attn) / 67,633,408 fallback.
//
// R11: flash LDS XOR-swizzle (T2): conflicts 6.29M -> 0. Kept.
// R12/R14/R16/R17 FAILED: flash pinned at ~62us (R13 shape FROZEN).
// R13: triple-buffer + counted vmcnt + ones-MFMA denom: 61.3us. KEPT.
// R15/R18: gemm_qkv8 256x288 at 1 block/CU (full-drain, then counted
// vmcnt): both ~neutral -> limiter is 1 block/CU (no co-resident block to
// cover stalls; only 2 waves/SIMD).
// R19: tile halved to 128x288 -> grid (8,64) = 512 blocks = 2 blocks/CU
// (LDS 3x26KB=78KB/block, 156KB/CU; 16 waves/CU). Same R18 pipeline:
// triple-buffer, prefetch distance 2, counted vmcnt(4) (4 loads/wave,
// 26 chunks padded to 32 slots). acc[2][9]; B-frags in 3 phases of 3 to
// stay under the 128-VGPR ceiling 4 waves/SIMD needs (launch_bounds 512,4).

typedef unsigned short u16;
typedef __attribute__((ext_vector_type(8))) short bf8;
typedef __attribute__((ext_vector_type(4))) short bf4;
typedef __attribute__((ext_vector_type(4))) int i4;
typedef __attribute__((ext_vector_type(4))) float f4;

#define MFMA16(a, b, c) __builtin_amdgcn_mfma_f32_16x16x32_bf16((a), (b), (c), 0, 0, 0)

#if __has_builtin(__builtin_amdgcn_exp2f)
#define EXP2(x) __builtin_amdgcn_exp2f(x)
#else
#define EXP2(x) __expf((x) * 0.6931471805599453f)
#endif

__device__ __forceinline__ float b2f(u16 h) {
  union { unsigned u; float f; } v; v.u = ((unsigned)h) << 16; return v.f;
}
__device__ __forceinline__ u16 f2b(float f) {
  union { float f; unsigned u; } v; v.f = f;
  unsigned r = v.u + 0x7fffu + ((v.u >> 16) & 1u);
  return (u16)(r >> 16);
}
// pack two fp32 -> (hi16(b)<<16)|hi16(a)  (truncation, P only)
__device__ __forceinline__ unsigned pack2(float a, float b) {
#if __has_builtin(__builtin_amdgcn_perm)
  return __builtin_amdgcn_perm(__builtin_bit_cast(unsigned, b),
                               __builtin_bit_cast(unsigned, a), 0x07060302u);
#else
  return (__builtin_bit_cast(unsigned, b) & 0xFFFF0000u) |
         (__builtin_bit_cast(unsigned, a) >> 16);
#endif
}
// async global->LDS 16B per lane; LDS dest = wave-uniform base + lane*16
__device__ __forceinline__ void gload16(const u16* g, u16* l) {
  __builtin_amdgcn_global_load_lds(
      (const __attribute__((address_space(1))) void*)g,
      (__attribute__((address_space(3))) void*)l, 16, 0, 0);
}
// wave-uniform dtype probe: 1 if x encodes fp32, 0 if bf16.
__device__ __forceinline__ int detect_f32(const u16* x) {
  unsigned v = x[2 * (threadIdx.x & 63)];
  unsigned e = (v >> 7) & 0xFF;
  return __ballot(e >= 0x8E) != 0ull;
}

// ---------------- prep: x convert + both weight transposes -----------------
// z=0: w_qkv transpose (72x24 tiles); z=1: w_proj (24x24); z=2: x convert.
__global__ __launch_bounds__(256) void prep(
    const void* __restrict__ x, u16* __restrict__ xbf,
    const void* __restrict__ wqkv, u16* __restrict__ wqkvT,
    const void* __restrict__ wproj, u16* __restrict__ wprojT) {
  const int z = blockIdx.z;
  if (z == 2) {  // convert 6,291,456 elems as 3,145,728 u32 pairs
    const int f32 = detect_f32((const u16*)x);
    const int lin = blockIdx.y * 72 + blockIdx.x;  // 0..1727
    if (f32) {
      const float2* in = (const float2*)x;
      unsigned* out = (unsigned*)xbf;
      for (int i = lin * 256 + threadIdx.x; i < 3145728; i += 442368) {
        float2 v = in[i];
        out[i] = (unsigned)f2b(v.x) | ((unsigned)f2b(v.y) << 16);
      }
    } else {
      const unsigned* in = (const unsigned*)x;
      unsigned* out = (unsigned*)xbf;
      for (int i = lin * 256 + threadIdx.x; i < 3145728; i += 442368)
        out[i] = in[i];
    }
    return;
  }
  if (z == 1 && blockIdx.x >= 24) return;
  const void* in = z ? wproj : wqkv;
  u16* out = z ? wprojT : wqkvT;
  const int R = 768, C = z ? 768 : 2304;
  __shared__ u16 tile[32][33];
  const int f32 = detect_f32((const u16*)x);
  const int bx = blockIdx.x * 32, by = blockIdx.y * 32;
  const int tx = threadIdx.x & 31, ty = threadIdx.x >> 5;
#pragma unroll
  for (int i = 0; i < 4; i++) {
    size_t idx = (size_t)(by + ty + i * 8) * C + bx + tx;
    tile[ty + i * 8][tx] = f32 ? f2b(((const float*)in)[idx]) : ((const u16*)in)[idx];
  }
  __syncthreads();
#pragma unroll
  for (int i = 0; i < 4; i++)
    out[(size_t)(bx + ty + i * 8) * R + by + tx] = tile[tx][ty + i * 8];
}

// ---------------- gemm_qkv8: qkv = xbf @ wqkvT^T, 128x288 tile, BK=32 ------
// M=8192 N=2304 K=768 hardcoded. Grid (8,64) = 512 blocks = 2 blocks/CU
// (16 waves/CU: inter-block overlap covers vmcnt waits + barriers). 8 waves:
// wr=wave>>1 (0..3) -> 32 rows (2 mt); wc=wave&1 -> 144 cols (9 ni).
// acc[2][9], 18 MFMA/group in 3 setprio phases of 3 B-frags (VGPR <= 128).
// Triple-buffered LDS (A 128x32 = 8KB + B 288x32 = 18KB = 26KB/buf, x3 =
// 78KB), prefetch distance 2, counted vmcnt(4) (26 chunks padded to 4/wave).
// R11 swizzle pair. Epilogue: cols<1536 -> qkv; >=1536 -> Vt key-permuted.
__global__ __launch_bounds__(512, 4) void gemm_qkv8(
    const u16* __restrict__ A, const u16* __restrict__ Bt,
    u16* __restrict__ Cq, u16* __restrict__ Vt) {
  __shared__ alignas(16) u16 L[3][13312];  // 3 x 26 KB = 78 KB
  const int t = threadIdx.x;
  const int lane = t & 63, wave = t >> 6;
  const int wr = wave >> 1, wc = wave & 1;
  const int quad = lane >> 4, l16 = lane & 15;
  const int bm = blockIdx.y * 128, bn = blockIdx.x * 288;
  const int dcol = ((lane & 3) ^ ((lane >> 3) & 3)) * 8;  // staging src swizzle
  const int swzU = (quad ^ ((l16 >> 1) & 3)) * 8;         // read-side swizzle
  const int drow = lane >> 2;                             // staging row in chunk
  f4 acc[2][9] = {};

  // stage K-group kt (cols kt*32..kt*32+31) into buf: 26 chunks of 16 rows
  // (A: c 0..7, B: c 8..25), padded to 4 loads/wave (uniform vmcnt).
#define STAGE(kt, buf)                                                       \
  {                                                                          \
    _Pragma("unroll")                                                        \
    for (int s = 0; s < 4; s++) {                                            \
      int c = wave + s * 8;                                                  \
      if (c >= 26) c = wave;  /* duplicate: same src+dst, benign */          \
      const int isB = c >= 8;                                                \
      const int rb = isB ? c - 8 : c;                                        \
      const u16* src = (isB ? Bt : A) +                                      \
          (size_t)((isB ? bn : bm) + rb * 16 + drow) * 768 +                 \
          (kt) * 32 + dcol;                                                  \
      u16* dst = &L[buf][(isB ? 4096 : 0) + rb * 512];                       \
      gload16(src, dst);                                                     \
    }                                                                        \
  }

  STAGE(0, 0);
  STAGE(1, 1);

  int cur = 0;
  for (int j = 0; j < 24; j++) {
    // group j's 4 loads retired; group j+1's 4 stay in flight across barrier
    if (j < 23) {
      asm volatile("s_waitcnt vmcnt(4)" ::: "memory");
    } else {
      asm volatile("s_waitcnt vmcnt(0)" ::: "memory");
    }
    __builtin_amdgcn_s_barrier();
    if (j + 2 < 24) {
      int pre = cur + 2; if (pre >= 3) pre -= 3;
      STAGE(j + 2, pre);
    }
    const u16* Lb = &L[cur][0];
    bf8 af[2];
#pragma unroll
    for (int m = 0; m < 2; m++)
      af[m] = *(const bf8*)&Lb[(wr * 32 + m * 16 + l16) * 32 + swzU];
#pragma unroll
    for (int p = 0; p < 3; p++) {
      bf8 bfr[3];
#pragma unroll
      for (int nn = 0; nn < 3; nn++)
        bfr[nn] = *(const bf8*)&Lb[4096 +
            (wc * 144 + (p * 3 + nn) * 16 + l16) * 32 + swzU];
      __builtin_amdgcn_s_setprio(1);
#pragma unroll
      for (int nn = 0; nn < 3; nn++)
#pragma unroll
        for (int m = 0; m < 2; m++)
          acc[m][p * 3 + nn] = MFMA16(af[m], bfr[nn], acc[m][p * 3 + nn]);
      __builtin_amdgcn_s_setprio(0);
    }
    cur = (cur == 2) ? 0 : cur + 1;
  }
#undef STAGE

  const int b_ = bm >> 11;
#pragma unroll
  for (int m = 0; m < 2; m++) {
    const int row0 = bm + wr * 32 + m * 16 + quad * 4;
    const int n0 = row0 & 2047;
    const int n2 = (n0 & ~31) | (((n0 >> 2) & 3) << 3) | (((n0 >> 4) & 1) << 2);
#pragma unroll
    for (int ni = 0; ni < 9; ni++) {
      const int col = bn + wc * 144 + ni * 16 + l16;
      if (col >= 1536) {  // V region -> transposed + key-permuted Vt
        const int colv = col - 1536, h = colv >> 6, d = colv & 63;
        bf4 pk = {(short)f2b(acc[m][ni][0]), (short)f2b(acc[m][ni][1]),
                  (short)f2b(acc[m][ni][2]), (short)f2b(acc[m][ni][3])};
        *(bf4*)&Vt[(size_t)((b_ * 12 + h) * 64 + d) * 2048 + n2] = pk;
      } else {  // Q/K region -> qkv
#pragma unroll
        for (int r = 0; r < 4; r++)
          Cq[(size_t)(row0 + r) * 2304 + col] = f2b(acc[m][ni][r]);
      }
    }
  }
}

// ---------------- GEMM C[M][N] = A[M][K] @ Bt[N][K]^T (+bias) --------------
// (proj + fused qattn normalize; QKV now handled by gemm_qkv8)
template <int BIAS, int QATTN>
__global__ __launch_bounds__(256, 4) void gemm_bt(
    const u16* __restrict__ A, const u16* __restrict__ Bt,
    const void* __restrict__ bias, void* __restrict__ C,
    int M, int Ncols, int K, const u16* __restrict__ xdet,
    u16* __restrict__ Vt, const float* __restrict__ qe,
    const float* __restrict__ lout) {
  if (QATTN && blockIdx.x == 6) {  // fused q_attn normalize
    const int f32o = detect_f32(xdet);
    const int base = blockIdx.y * 1536;
    for (int j = threadIdx.x; j < 1536; j += 256) {
      int idx = base + j;
      float v = qe[idx] * (1.f / lout[idx >> 11]);
      size_t oidx = (size_t)6291456 + idx;
      if (f32o) ((float*)C)[oidx] = v; else ((u16*)C)[oidx] = f2b(v);
    }
    return;
  }
  __shared__ alignas(16) u16 Al[2][128 * 32];
  __shared__ alignas(16) u16 Bl[2][128 * 32];
  const int t = threadIdx.x;
  const int lane = t & 63, wave = t >> 6;
  const int wr = wave >> 1, wc = wave & 1;
  const int quad = lane >> 4, l16 = lane & 15;
  const int bm = blockIdx.y * 128, bn = blockIdx.x * 128;
  const int f32o = BIAS ? detect_f32(xdet) : 0;
  const int grow = lane >> 2, gcol = (lane & 3) * 8;
  const int chunk0 = wave * 2, chunk1 = wave * 2 + 1;
  const int arow0 = chunk0 * 16 + grow, arow1 = chunk1 * 16 + grow;
  f4 acc[4][4] = {};
  gload16(A + (size_t)(bm + arow0) * K + gcol, &Al[0][chunk0 * 512]);
  gload16(Bt + (size_t)(bn + arow0) * K + gcol, &Bl[0][chunk0 * 512]);
  gload16(A + (size_t)(bm + arow1) * K + gcol, &Al[0][chunk1 * 512]);
  gload16(Bt + (size_t)(bn + arow1) * K + gcol, &Bl[0][chunk1 * 512]);
  const int NIT = K >> 5;
  for (int i = 0; i < NIT; i++) {
    const int cur = i & 1, nxt = cur ^ 1;
    __syncthreads();
    if (i + 1 < NIT) {
      int k0 = (i + 1) << 5;
      gload16(A + (size_t)(bm + arow0) * K + k0 + gcol, &Al[nxt][chunk0 * 512]);
      gload16(Bt + (size_t)(bn + arow0) * K + k0 + gcol, &Bl[nxt][chunk0 * 512]);
      gload16(A + (size_t)(bm + arow1) * K + k0 + gcol, &Al[nxt][chunk1 * 512]);
      gload16(Bt + (size_t)(bn + arow1) * K + k0 + gcol, &Bl[nxt][chunk1 * 512]);
    }
    bf8 af[4], bfr[4];
#pragma unroll
    for (int mt = 0; mt < 4; mt++)
      af[mt] = *(const bf8*)&Al[cur][(wr * 64 + mt * 16 + l16) * 32 + quad * 8];
#pragma unroll
    for (int nt = 0; nt < 4; nt++)
      bfr[nt] = *(const bf8*)&Bl[cur][(wc * 64 + nt * 16 + l16) * 32 + quad * 8];
#pragma unroll
    for (int mt = 0; mt < 4; mt++)
#pragma unroll
      for (int nt = 0; nt < 4; nt++)
        acc[mt][nt] = MFMA16(af[mt], bfr[nt], acc[mt][nt]);
  }
  if (Vt != nullptr && bn >= 1536) {
    const int b = bm >> 11;
#pragma unroll
    for (int mt = 0; mt < 4; mt++) {
      int n0 = (bm & 2047) + wr * 64 + mt * 16 + quad * 4;
      int n2 = (n0 & ~31) | (((n0 >> 2) & 3) << 3) | (((n0 >> 4) & 1) << 2);
#pragma unroll
      for (int nt = 0; nt < 4; nt++) {
        int colv = bn - 1536 + wc * 64 + nt * 16 + l16;
        int h = colv >> 6, d = colv & 63;
        bf4 pk = {(short)f2b(acc[mt][nt][0]), (short)f2b(acc[mt][nt][1]),
                  (short)f2b(acc[mt][nt][2]), (short)f2b(acc[mt][nt][3])};
        *(bf4*)&Vt[(size_t)((b * 12 + h) * 64 + d) * 2048 + n2] = pk;
      }
    }
    return;
  }
#pragma unroll
  for (int mt = 0; mt < 4; mt++) {
    int row = bm + wr * 64 + mt * 16 + quad * 4;
#pragma unroll
    for (int nt = 0; nt < 4; nt++) {
      int col = bn + wc * 64 + nt * 16 + l16;
      float bv = 0.f;
      if (BIAS)
        bv = f32o ? ((const float*)bias)[col] : b2f(((const u16*)bias)[col]);
#pragma unroll
      for (int r = 0; r < 4; r++) {
        size_t idx = (size_t)(row + r) * Ncols + col;
        float v = acc[mt][nt][r] + bv;
        if (f32o) ((float*)C)[idx] = v; else ((u16*)C)[idx] = f2b(v);
      }
    }
  }
}

// ---------------- flash attention v10 (R13, FROZEN): triple-buffer ---------
// Per buffer: K0|K1|V0|V1, each 64 rows x 32 cols, 64B rows, XOR-swizzled
// (R11). 4 gload16/wave per tile. Raw s_barrier + s_waitcnt vmcnt(4): the
// next tile's DMA stays in flight across the barrier (T3/T4); each tile has
// 2 compute phases to land. Softmax denominator via ones-row MFMA (lacc).
// Fixed-max exp2 softmax (-M0 in MFMA C init); P in B-fragment registers
// (V key-permuted by gemm-QKV epilogue); P packed via v_perm_b32.
__global__ __launch_bounds__(256, 3) void flash_attn(
    const u16* __restrict__ qkv, const u16* __restrict__ Vt,
    u16* __restrict__ O, float* __restrict__ qe, float* __restrict__ lout) {
  __shared__ alignas(16) u16 lds[3][8192];  // 3 x 16 KB
  const int t = threadIdx.x, lane = t & 63, wave = t >> 6;
  const int quad = lane >> 4, l16 = lane & 15;
  const int id = blockIdx.x;
  const int bh = (id & 7) + 8 * (id >> 7);
  const int qtile = (id >> 3) & 15;
  const int b = bh / 12, h = bh - b * 12;
  const int q0 = qtile * 128 + wave * 32;
  const bool dumpP = (qe != nullptr) && (qtile == 0) && (wave == 0);
  const float SCALE2 = 0.125f * 1.44269504089f;
  const float mM0 = -16.f;
  bf8 qf[2][2];
#pragma unroll
  for (int qt = 0; qt < 2; qt++) {
    const u16* Qr = qkv + (size_t)(b * 2048 + q0 + qt * 16 + l16) * 2304 + h * 64;
    bf8 r0 = *(const bf8*)(Qr + quad * 8);
    bf8 r1 = *(const bf8*)(Qr + 32 + quad * 8);
#pragma unroll
    for (int j = 0; j < 8; j++) {
      qf[qt][0][j] = (short)f2b(b2f((u16)r0[j]) * SCALE2);
      qf[qt][1][j] = (short)f2b(b2f((u16)r1[j]) * SCALE2);
    }
  }
  bf8 ones;
#pragma unroll
  for (int j = 0; j < 8; j++) ones[j] = (short)0x3F80;
  const u16* Kb = qkv + (size_t)(b * 2048) * 2304 + 768 + h * 64;
  const u16* Vb = Vt + (size_t)((b * 12 + h) * 64) * 2048;
  const int drow = wave * 16 + (lane >> 2);  // DMA row within 64-row tiles
  // T2: pre-swizzled global source col; LDS dest stays linear (lane*16).
  const int dcol = ((lane & 3) ^ ((lane >> 3) & 3)) * 8;
  // T2: matching read-side col swizzle ((row>>1)&3 == (l16>>1)&3 here).
  const int swz = (quad ^ ((l16 >> 1) & 3)) * 8;
  f4 o[2][4] = {};
  f4 lacc[2] = {};

#define STAGE(tile, buf)                                            \
  {                                                                 \
    int n1_ = (tile) * 64;                                          \
    const u16* Kt_ = Kb + (size_t)(n1_ + drow) * 2304 + dcol;       \
    const u16* Vr_ = Vb + (size_t)drow * 2048 + n1_ + dcol;         \
    u16* base_ = &lds[buf][wave * 512];                             \
    gload16(Kt_, base_);                                            \
    gload16(Kt_ + 32, base_ + 2048);                                \
    gload16(Vr_, base_ + 4096);                                     \
    gload16(Vr_ + 32, base_ + 6144);                                \
  }

  STAGE(0, 0);
  STAGE(1, 1);

  int cur = 0;
  for (int i = 0; i < 32; i++) {
    // tile i's 4 loads retired; tile i+1's 4 stay in flight across barrier
    if (i < 31) {
      asm volatile("s_waitcnt vmcnt(4)" ::: "memory");
    } else {
      asm volatile("s_waitcnt vmcnt(0)" ::: "memory");
    }
    __builtin_amdgcn_s_barrier();
    // prefetch tile i+2 into buf (cur+2)%3 (its last reader finished
    // before the barrier above)
    if (i + 2 < 32) {
      int pre = cur + 2; if (pre >= 3) pre -= 3;
      STAGE(i + 2, pre);
    }
    const u16* K0 = &lds[cur][0];
    const u16* K1 = &lds[cur][2048];
    // S^T (exp2 domain, -M0 pre-folded) -> P in B-fragment registers
    union { i4 i; bf8 b; } pf[2][2];
#pragma unroll
    for (int kt = 0; kt < 4; kt++) {
      bf8 kf0 = *(const bf8*)&K0[(kt * 16 + l16) * 32 + swz];
      bf8 kf1 = *(const bf8*)&K1[(kt * 16 + l16) * 32 + swz];
#pragma unroll
      for (int qt = 0; qt < 2; qt++) {
        f4 z = {mM0, mM0, mM0, mM0};
        z = MFMA16(kf0, qf[qt][0], z);
        z = MFMA16(kf1, qf[qt][1], z);
        float e0 = EXP2(z[0]);
        float e1 = EXP2(z[1]);
        float e2 = EXP2(z[2]);
        float e3 = EXP2(z[3]);
        if (qt == 0 && dumpP && l16 == 0) {
          f4 ev = {e0, e1, e2, e3};
          *(f4*)&qe[bh * 2048 + i * 64 + kt * 16 + quad * 4] = ev;
        }
        pf[qt][kt >> 1].i[(kt & 1) * 2 + 0] = (int)pack2(e0, e1);
        pf[qt][kt >> 1].i[(kt & 1) * 2 + 1] = (int)pack2(e2, e3);
      }
    }
#pragma unroll
    for (int pair = 0; pair < 2; pair++) {
      const u16* Vp = &lds[cur][4096 + pair * 2048];
      lacc[0] = MFMA16(ones, pf[0][pair].b, lacc[0]);
      lacc[1] = MFMA16(ones, pf[1][pair].b, lacc[1]);
#pragma unroll
      for (int nt = 0; nt < 4; nt++) {
        bf8 vf = *(const bf8*)&Vp[(nt * 16 + l16) * 32 + swz];
        o[0][nt] = MFMA16(vf, pf[0][pair].b, o[0][nt]);
        o[1][nt] = MFMA16(vf, pf[1][pair].b, o[1][nt]);
      }
    }
    cur = (cur == 2) ? 0 : cur + 1;
  }
#undef STAGE
#pragma unroll
  for (int qt = 0; qt < 2; qt++) {
    float l = lacc[qt][0];  // every lane: full denom for its q-column
    if (qt == 0 && dumpP && lane == 0) lout[bh] = l;
    float inv = 1.f / l;
    size_t row = (size_t)(b * 2048 + q0 + qt * 16 + l16) * 768 + h * 64;
#pragma unroll
    for (int nt = 0; nt < 4; nt++) {
      bf4 pk = {(short)f2b(o[qt][nt][0] * inv), (short)f2b(o[qt][nt][1] * inv),
                (short)f2b(o[qt][nt][2] * inv), (short)f2b(o[qt][nt][3] * inv)};
      *(bf4*)&O[row + nt * 16 + quad * 4] = pk;
    }
  }
}

// ---------------- fallback q_attn (if workspace too small) -----------------
__global__ __launch_bounds__(256) void qattn_row0(
    const u16* __restrict__ qkv, void* __restrict__ out,
    const u16* __restrict__ xdet) {
  const int bh = blockIdx.x, b = bh / 12, h = bh % 12;
  __shared__ float qs[64];
  __shared__ float sv[2048];
  __shared__ float red[8];
  const int t = threadIdx.x;
  const int f32o = detect_f32(xdet);
  if (t < 64) qs[t] = b2f(qkv[(size_t)(b * 2048) * 2304 + h * 64 + t]);
  __syncthreads();
  float lmax = -1e30f;
  for (int k = t; k < 2048; k += 256) {
    const u16* Kr = qkv + (size_t)(b * 2048 + k) * 2304 + 768 + h * 64;
    float acc = 0.f;
#pragma unroll
    for (int j = 0; j < 8; j++) {
      bf8 kv = *(const bf8*)(Kr + j * 8);
#pragma unroll
      for (int d = 0; d < 8; d++) acc += qs[j * 8 + d] * b2f((u16)kv[d]);
    }
    acc *= 0.125f;
    sv[k] = acc;
    lmax = fmaxf(lmax, acc);
  }
#pragma unroll
  for (int off = 32; off >= 1; off >>= 1) lmax = fmaxf(lmax, __shfl_xor(lmax, off, 64));
  if ((t & 63) == 0) red[t >> 6] = lmax;
  __syncthreads();
  const float bmax = fmaxf(fmaxf(red[0], red[1]), fmaxf(red[2], red[3]));
  float lsum = 0.f;
  for (int k = t; k < 2048; k += 256) {
    float e = __expf(sv[k] - bmax);
    sv[k] = e;
    lsum += e;
  }
#pragma unroll
  for (int off = 32; off >= 1; off >>= 1) lsum += __shfl_xor(lsum, off, 64);
  if ((t & 63) == 0) red[4 + (t >> 6)] = lsum;
  __syncthreads();
  const float inv = 1.f / (red[4] + red[5] + red[6] + red[7]);
  for (int k = t; k < 2048; k += 256) {
    size_t idx = (size_t)6291456 + (size_t)bh * 2048 + k;
    float v = sv[k] * inv;
    if (f32o) ((float*)out)[idx] = v; else ((u16*)out)[idx] = f2b(v);
  }
}

extern "C" void kernel_launch(void* const* d_in, const int* in_sizes, int n_in,
                              void* d_out, int out_size, void* d_ws, size_t ws_size,
                              hipStream_t stream) {
  const void* x_raw      = d_in[0];
  const void* w_qkv_raw  = d_in[1];
  const void* w_proj_raw = d_in[2];
  const void* b_proj_raw = d_in[3];
  const u16* xdet = (const u16*)x_raw;
  char* ws = (char*)d_ws;
  u16* xbf    = (u16*)(ws + 256);            // 12,582,912 B (aliased by attn later)
  u16* wqkvT  = (u16*)(ws + 12583168);       //  3,538,944 B
  u16* wprojT = (u16*)(ws + 16122112);       //  1,179,648 B
  u16* qkv    = (u16*)(ws + 17301760);       // 37,748,736 B (V region unused)
  u16* Vt     = (u16*)(ws + 55050496);       // 12,582,912 B -> 67,633,408
  float* qe   = (float*)(ws + 67633408);     //    393,216 B
  float* lout = (float*)(ws + 68026624);     //        192 B -> 68,026,816
  u16* attn   = xbf;
  const bool fused = ws_size >= 68026816ull;

  prep<<<dim3(72, 24, 3), 256, 0, stream>>>(
      x_raw, xbf, w_qkv_raw, wqkvT, w_proj_raw, wprojT);
  gemm_qkv8<<<dim3(8, 64), 512, 0, stream>>>(xbf, wqkvT, qkv, Vt);
  flash_attn<<<dim3(768), 256, 0, stream>>>(qkv, Vt, attn,
                                            fused ? qe : nullptr,
                                            fused ? lout : nullptr);
  if (fused) {
    gemm_bt<1, 1><<<dim3(7, 64), 256, 0, stream>>>(
        attn, wprojT, b_proj_raw, d_out, 8192, 768, 768, xdet, nullptr, qe, lout);
  } else {
    gemm_bt<1, 0><<<dim3(6, 64), 256, 0, stream>>>(
        attn, wprojT, b_proj_raw, d_out, 8192, 768, 768, xdet, nullptr, nullptr, nullptr);
    qattn_row0<<<dim3(48), 256, 0, stream>>>(qkv, d_out, xdet);
  }
}

// Round 10
// 208.153 us; speedup vs baseline: 1.0044x; 1.0044x over previous
//
#include <hip/hip_runtime.h>

// Attention_53798760350071: B=4 N=2048 D=768 H=12 HD=64, SCALE=0.125
// Dtype-agnostic (inline 64-sample ballot detection); bf16 MFMA pipeline.
// d_out = [proj_out (4,2048,768)] ++ [q_attn (4,12,2048)].
// Workspace: 68,026,816 bytes (fused q_attn) / 67,633,408 fallback.
//
// R11: flash LDS XOR-swizzle (T2): conflicts 6.29M -> 0. Kept.
// R12/R14/R16/R17 FAILED: flash pinned at ~61us (R13 shape FROZEN; FLOP
// check: 946 TF = 38% peak, MFMA+trans co-limited, 82% combined util).
// R13: triple-buffer + counted vmcnt + ones-MFMA denom: 61.3us. KEPT.
// R15/R18/R19: three gemm_qkv8 structures all ~neutral at total level.
// R20: gemm_proj was the last untouched kernel — old 2-phase gemm_bt at
// grid (7,64) = 1.5 real blocks/CU (guaranteed tail imbalance). New
// gemm_proj4: 64x128 tile, BK=32, grid (7,128) = 768 real blocks = 3/CU
// even, flash-R18 pipeline (triple buffer 3x12KB, prefetch distance 2,
// counted vmcnt(3), 12 chunks = exactly 3 loads/wave), R11 swizzle pair.
// qattn normalize stays fused (bx==6, by<64). Fallback path unchanged.

typedef unsigned short u16;
typedef __attribute__((ext_vector_type(8))) short bf8;
typedef __attribute__((ext_vector_type(4))) short bf4;
typedef __attribute__((ext_vector_type(4))) int i4;
typedef __attribute__((ext_vector_type(4))) float f4;

#define MFMA16(a, b, c) __builtin_amdgcn_mfma_f32_16x16x32_bf16((a), (b), (c), 0, 0, 0)

#if __has_builtin(__builtin_amdgcn_exp2f)
#define EXP2(x) __builtin_amdgcn_exp2f(x)
#else
#define EXP2(x) __expf((x) * 0.6931471805599453f)
#endif

__device__ __forceinline__ float b2f(u16 h) {
  union { unsigned u; float f; } v; v.u = ((unsigned)h) << 16; return v.f;
}
__device__ __forceinline__ u16 f2b(float f) {
  union { float f; unsigned u; } v; v.f = f;
  unsigned r = v.u + 0x7fffu + ((v.u >> 16) & 1u);
  return (u16)(r >> 16);
}
// pack two fp32 -> (hi16(b)<<16)|hi16(a)  (truncation, P only)
__device__ __forceinline__ unsigned pack2(float a, float b) {
#if __has_builtin(__builtin_amdgcn_perm)
  return __builtin_amdgcn_perm(__builtin_bit_cast(unsigned, b),
                               __builtin_bit_cast(unsigned, a), 0x07060302u);
#else
  return (__builtin_bit_cast(unsigned, b) & 0xFFFF0000u) |
         (__builtin_bit_cast(unsigned, a) >> 16);
#endif
}
// async global->LDS 16B per lane; LDS dest = wave-uniform base + lane*16
__device__ __forceinline__ void gload16(const u16* g, u16* l) {
  __builtin_amdgcn_global_load_lds(
      (const __attribute__((address_space(1))) void*)g,
      (__attribute__((address_space(3))) void*)l, 16, 0, 0);
}
// wave-uniform dtype probe: 1 if x encodes fp32, 0 if bf16.
__device__ __forceinline__ int detect_f32(const u16* x) {
  unsigned v = x[2 * (threadIdx.x & 63)];
  unsigned e = (v >> 7) & 0xFF;
  return __ballot(e >= 0x8E) != 0ull;
}

// ---------------- prep: x convert + both weight transposes -----------------
// z=0: w_qkv transpose (72x24 tiles); z=1: w_proj (24x24); z=2: x convert.
__global__ __launch_bounds__(256) void prep(
    const void* __restrict__ x, u16* __restrict__ xbf,
    const void* __restrict__ wqkv, u16* __restrict__ wqkvT,
    const void* __restrict__ wproj, u16* __restrict__ wprojT) {
  const int z = blockIdx.z;
  if (z == 2) {  // convert 6,291,456 elems as 3,145,728 u32 pairs
    const int f32 = detect_f32((const u16*)x);
    const int lin = blockIdx.y * 72 + blockIdx.x;  // 0..1727
    if (f32) {
      const float2* in = (const float2*)x;
      unsigned* out = (unsigned*)xbf;
      for (int i = lin * 256 + threadIdx.x; i < 3145728; i += 442368) {
        float2 v = in[i];
        out[i] = (unsigned)f2b(v.x) | ((unsigned)f2b(v.y) << 16);
      }
    } else {
      const unsigned* in = (const unsigned*)x;
      unsigned* out = (unsigned*)xbf;
      for (int i = lin * 256 + threadIdx.x; i < 3145728; i += 442368)
        out[i] = in[i];
    }
    return;
  }
  if (z == 1 && blockIdx.x >= 24) return;
  const void* in = z ? wproj : wqkv;
  u16* out = z ? wprojT : wqkvT;
  const int R = 768, C = z ? 768 : 2304;
  __shared__ u16 tile[32][33];
  const int f32 = detect_f32((const u16*)x);
  const int bx = blockIdx.x * 32, by = blockIdx.y * 32;
  const int tx = threadIdx.x & 31, ty = threadIdx.x >> 5;
#pragma unroll
  for (int i = 0; i < 4; i++) {
    size_t idx = (size_t)(by + ty + i * 8) * C + bx + tx;
    tile[ty + i * 8][tx] = f32 ? f2b(((const float*)in)[idx]) : ((const u16*)in)[idx];
  }
  __syncthreads();
#pragma unroll
  for (int i = 0; i < 4; i++)
    out[(size_t)(bx + ty + i * 8) * R + by + tx] = tile[tx][ty + i * 8];
}

// ---------------- gemm_qkv8: qkv = xbf @ wqkvT^T, 128x288 tile, BK=32 ------
// M=8192 N=2304 K=768 hardcoded. Grid (8,64) = 512 blocks = 2 blocks/CU.
// 8 waves: wr=wave>>1 (0..3) -> 32 rows (2 mt); wc=wave&1 -> 144 cols (9 ni).
// acc[2][9], 18 MFMA/group in 3 setprio phases. Triple-buffered LDS (26KB x3
// = 78KB), prefetch distance 2, counted vmcnt(4) (26 chunks padded 4/wave).
// R11 swizzle pair. Epilogue: cols<1536 -> qkv; >=1536 -> Vt key-permuted.
__global__ __launch_bounds__(512, 4) void gemm_qkv8(
    const u16* __restrict__ A, const u16* __restrict__ Bt,
    u16* __restrict__ Cq, u16* __restrict__ Vt) {
  __shared__ alignas(16) u16 L[3][13312];  // 3 x 26 KB = 78 KB
  const int t = threadIdx.x;
  const int lane = t & 63, wave = t >> 6;
  const int wr = wave >> 1, wc = wave & 1;
  const int quad = lane >> 4, l16 = lane & 15;
  const int bm = blockIdx.y * 128, bn = blockIdx.x * 288;
  const int dcol = ((lane & 3) ^ ((lane >> 3) & 3)) * 8;  // staging src swizzle
  const int swzU = (quad ^ ((l16 >> 1) & 3)) * 8;         // read-side swizzle
  const int drow = lane >> 2;                             // staging row in chunk
  f4 acc[2][9] = {};

#define STAGE(kt, buf)                                                       \
  {                                                                          \
    _Pragma("unroll")                                                        \
    for (int s = 0; s < 4; s++) {                                            \
      int c = wave + s * 8;                                                  \
      if (c >= 26) c = wave;  /* duplicate: same src+dst, benign */          \
      const int isB = c >= 8;                                                \
      const int rb = isB ? c - 8 : c;                                        \
      const u16* src = (isB ? Bt : A) +                                      \
          (size_t)((isB ? bn : bm) + rb * 16 + drow) * 768 +                 \
          (kt) * 32 + dcol;                                                  \
      u16* dst = &L[buf][(isB ? 4096 : 0) + rb * 512];                       \
      gload16(src, dst);                                                     \
    }                                                                        \
  }

  STAGE(0, 0);
  STAGE(1, 1);

  int cur = 0;
  for (int j = 0; j < 24; j++) {
    if (j < 23) {
      asm volatile("s_waitcnt vmcnt(4)" ::: "memory");
    } else {
      asm volatile("s_waitcnt vmcnt(0)" ::: "memory");
    }
    __builtin_amdgcn_s_barrier();
    if (j + 2 < 24) {
      int pre = cur + 2; if (pre >= 3) pre -= 3;
      STAGE(j + 2, pre);
    }
    const u16* Lb = &L[cur][0];
    bf8 af[2];
#pragma unroll
    for (int m = 0; m < 2; m++)
      af[m] = *(const bf8*)&Lb[(wr * 32 + m * 16 + l16) * 32 + swzU];
#pragma unroll
    for (int p = 0; p < 3; p++) {
      bf8 bfr[3];
#pragma unroll
      for (int nn = 0; nn < 3; nn++)
        bfr[nn] = *(const bf8*)&Lb[4096 +
            (wc * 144 + (p * 3 + nn) * 16 + l16) * 32 + swzU];
      __builtin_amdgcn_s_setprio(1);
#pragma unroll
      for (int nn = 0; nn < 3; nn++)
#pragma unroll
        for (int m = 0; m < 2; m++)
          acc[m][p * 3 + nn] = MFMA16(af[m], bfr[nn], acc[m][p * 3 + nn]);
      __builtin_amdgcn_s_setprio(0);
    }
    cur = (cur == 2) ? 0 : cur + 1;
  }
#undef STAGE

  const int b_ = bm >> 11;
#pragma unroll
  for (int m = 0; m < 2; m++) {
    const int row0 = bm + wr * 32 + m * 16 + quad * 4;
    const int n0 = row0 & 2047;
    const int n2 = (n0 & ~31) | (((n0 >> 2) & 3) << 3) | (((n0 >> 4) & 1) << 2);
#pragma unroll
    for (int ni = 0; ni < 9; ni++) {
      const int col = bn + wc * 144 + ni * 16 + l16;
      if (col >= 1536) {  // V region -> transposed + key-permuted Vt
        const int colv = col - 1536, h = colv >> 6, d = colv & 63;
        bf4 pk = {(short)f2b(acc[m][ni][0]), (short)f2b(acc[m][ni][1]),
                  (short)f2b(acc[m][ni][2]), (short)f2b(acc[m][ni][3])};
        *(bf4*)&Vt[(size_t)((b_ * 12 + h) * 64 + d) * 2048 + n2] = pk;
      } else {  // Q/K region -> qkv
#pragma unroll
        for (int r = 0; r < 4; r++)
          Cq[(size_t)(row0 + r) * 2304 + col] = f2b(acc[m][ni][r]);
      }
    }
  }
}

// ---------------- gemm_proj4: d_out = attn @ wprojT^T + bias ---------------
// M=8192 N=768 K=768. Tile 64x128, BK=32, grid (7,128): bx<6 gemm (768
// blocks = 3/CU even), bx==6 & by<64: fused q_attn normalize. 4 waves:
// wr=wave>>1 (0..1) -> 32 rows (2 mt); wc=wave&1 -> 64 cols (4 nt).
// acc[2][4], 8 MFMA/group. Triple-buffered LDS (A 4KB + B 8KB = 12KB x3),
// prefetch distance 2, counted vmcnt(3) (12 chunks = exactly 3/wave).
// R11 swizzle pair. Output f32/bf16 by input-dtype detect; bias added.
__global__ __launch_bounds__(256, 3) void gemm_proj4(
    const u16* __restrict__ A, const u16* __restrict__ Bt,
    const void* __restrict__ bias, void* __restrict__ C,
    const u16* __restrict__ xdet, const float* __restrict__ qe,
    const float* __restrict__ lout) {
  if (blockIdx.x == 6) {  // fused q_attn normalize (64 working blocks)
    if (blockIdx.y >= 64) return;
    const int f32o = detect_f32(xdet);
    const int base = blockIdx.y * 1536;
    for (int j = threadIdx.x; j < 1536; j += 256) {
      int idx = base + j;
      float v = qe[idx] * (1.f / lout[idx >> 11]);
      size_t oidx = (size_t)6291456 + idx;
      if (f32o) ((float*)C)[oidx] = v; else ((u16*)C)[oidx] = f2b(v);
    }
    return;
  }
  __shared__ alignas(16) u16 L[3][6144];  // 3 x 12 KB
  const int t = threadIdx.x;
  const int lane = t & 63, wave = t >> 6;
  const int wr = wave >> 1, wc = wave & 1;
  const int quad = lane >> 4, l16 = lane & 15;
  const int bm = blockIdx.y * 64, bn = blockIdx.x * 128;
  const int f32o = detect_f32(xdet);
  const int dcol = ((lane & 3) ^ ((lane >> 3) & 3)) * 8;  // staging src swizzle
  const int swzU = (quad ^ ((l16 >> 1) & 3)) * 8;         // read-side swizzle
  const int drow = lane >> 2;                             // staging row in chunk
  f4 acc[2][4] = {};

  // 12 chunks of 16 rows: A c 0..3 (64 rows), B c 4..11 (128 rows);
  // exactly 3 loads/wave (c = wave + s*4).
#define STAGE(kt, buf)                                                       \
  {                                                                          \
    _Pragma("unroll")                                                        \
    for (int s = 0; s < 3; s++) {                                            \
      const int c = wave + s * 4;                                            \
      const int isB = c >= 4;                                                \
      const int rb = isB ? c - 4 : c;                                        \
      const u16* src = (isB ? Bt : A) +                                      \
          (size_t)((isB ? bn : bm) + rb * 16 + drow) * 768 +                 \
          (kt) * 32 + dcol;                                                  \
      u16* dst = &L[buf][(isB ? 2048 : 0) + rb * 512];                       \
      gload16(src, dst);                                                     \
    }                                                                        \
  }

  STAGE(0, 0);
  STAGE(1, 1);

  int cur = 0;
  for (int j = 0; j < 24; j++) {
    // group j's 3 loads retired; group j+1's 3 stay in flight across barrier
    if (j < 23) {
      asm volatile("s_waitcnt vmcnt(3)" ::: "memory");
    } else {
      asm volatile("s_waitcnt vmcnt(0)" ::: "memory");
    }
    __builtin_amdgcn_s_barrier();
    if (j + 2 < 24) {
      int pre = cur + 2; if (pre >= 3) pre -= 3;
      STAGE(j + 2, pre);
    }
    const u16* Lb = &L[cur][0];
    bf8 af[2], bfr[4];
#pragma unroll
    for (int m = 0; m < 2; m++)
      af[m] = *(const bf8*)&Lb[(wr * 32 + m * 16 + l16) * 32 + swzU];
#pragma unroll
    for (int nt = 0; nt < 4; nt++)
      bfr[nt] = *(const bf8*)&Lb[2048 + (wc * 64 + nt * 16 + l16) * 32 + swzU];
    __builtin_amdgcn_s_setprio(1);
#pragma unroll
    for (int nt = 0; nt < 4; nt++)
#pragma unroll
      for (int m = 0; m < 2; m++)
        acc[m][nt] = MFMA16(af[m], bfr[nt], acc[m][nt]);
    __builtin_amdgcn_s_setprio(0);
    cur = (cur == 2) ? 0 : cur + 1;
  }
#undef STAGE

#pragma unroll
  for (int m = 0; m < 2; m++) {
    const int row0 = bm + wr * 32 + m * 16 + quad * 4;
#pragma unroll
    for (int nt = 0; nt < 4; nt++) {
      const int col = bn + wc * 64 + nt * 16 + l16;
      const float bv = f32o ? ((const float*)bias)[col]
                            : b2f(((const u16*)bias)[col]);
#pragma unroll
      for (int r = 0; r < 4; r++) {
        size_t idx = (size_t)(row0 + r) * 768 + col;
        float v = acc[m][nt][r] + bv;
        if (f32o) ((float*)C)[idx] = v; else ((u16*)C)[idx] = f2b(v);
      }
    }
  }
}

// ---------------- GEMM C[M][N] = A[M][K] @ Bt[N][K]^T (+bias) --------------
// (fallback-path proj only)
template <int BIAS, int QATTN>
__global__ __launch_bounds__(256, 4) void gemm_bt(
    const u16* __restrict__ A, const u16* __restrict__ Bt,
    const void* __restrict__ bias, void* __restrict__ C,
    int M, int Ncols, int K, const u16* __restrict__ xdet,
    u16* __restrict__ Vt, const float* __restrict__ qe,
    const float* __restrict__ lout) {
  if (QATTN && blockIdx.x == 6) {  // fused q_attn normalize
    const int f32o = detect_f32(xdet);
    const int base = blockIdx.y * 1536;
    for (int j = threadIdx.x; j < 1536; j += 256) {
      int idx = base + j;
      float v = qe[idx] * (1.f / lout[idx >> 11]);
      size_t oidx = (size_t)6291456 + idx;
      if (f32o) ((float*)C)[oidx] = v; else ((u16*)C)[oidx] = f2b(v);
    }
    return;
  }
  __shared__ alignas(16) u16 Al[2][128 * 32];
  __shared__ alignas(16) u16 Bl[2][128 * 32];
  const int t = threadIdx.x;
  const int lane = t & 63, wave = t >> 6;
  const int wr = wave >> 1, wc = wave & 1;
  const int quad = lane >> 4, l16 = lane & 15;
  const int bm = blockIdx.y * 128, bn = blockIdx.x * 128;
  const int f32o = BIAS ? detect_f32(xdet) : 0;
  const int grow = lane >> 2, gcol = (lane & 3) * 8;
  const int chunk0 = wave * 2, chunk1 = wave * 2 + 1;
  const int arow0 = chunk0 * 16 + grow, arow1 = chunk1 * 16 + grow;
  f4 acc[4][4] = {};
  gload16(A + (size_t)(bm + arow0) * K + gcol, &Al[0][chunk0 * 512]);
  gload16(Bt + (size_t)(bn + arow0) * K + gcol, &Bl[0][chunk0 * 512]);
  gload16(A + (size_t)(bm + arow1) * K + gcol, &Al[0][chunk1 * 512]);
  gload16(Bt + (size_t)(bn + arow1) * K + gcol, &Bl[0][chunk1 * 512]);
  const int NIT = K >> 5;
  for (int i = 0; i < NIT; i++) {
    const int cur = i & 1, nxt = cur ^ 1;
    __syncthreads();
    if (i + 1 < NIT) {
      int k0 = (i + 1) << 5;
      gload16(A + (size_t)(bm + arow0) * K + k0 + gcol, &Al[nxt][chunk0 * 512]);
      gload16(Bt + (size_t)(bn + arow0) * K + k0 + gcol, &Bl[nxt][chunk0 * 512]);
      gload16(A + (size_t)(bm + arow1) * K + k0 + gcol, &Al[nxt][chunk1 * 512]);
      gload16(Bt + (size_t)(bn + arow1) * K + k0 + gcol, &Bl[nxt][chunk1 * 512]);
    }
    bf8 af[4], bfr[4];
#pragma unroll
    for (int mt = 0; mt < 4; mt++)
      af[mt] = *(const bf8*)&Al[cur][(wr * 64 + mt * 16 + l16) * 32 + quad * 8];
#pragma unroll
    for (int nt = 0; nt < 4; nt++)
      bfr[nt] = *(const bf8*)&Bl[cur][(wc * 64 + nt * 16 + l16) * 32 + quad * 8];
#pragma unroll
    for (int mt = 0; mt < 4; mt++)
#pragma unroll
      for (int nt = 0; nt < 4; nt++)
        acc[mt][nt] = MFMA16(af[mt], bfr[nt], acc[mt][nt]);
  }
  if (Vt != nullptr && bn >= 1536) {
    const int b = bm >> 11;
#pragma unroll
    for (int mt = 0; mt < 4; mt++) {
      int n0 = (bm & 2047) + wr * 64 + mt * 16 + quad * 4;
      int n2 = (n0 & ~31) | (((n0 >> 2) & 3) << 3) | (((n0 >> 4) & 1) << 2);
#pragma unroll
      for (int nt = 0; nt < 4; nt++) {
        int colv = bn - 1536 + wc * 64 + nt * 16 + l16;
        int h = colv >> 6, d = colv & 63;
        bf4 pk = {(short)f2b(acc[mt][nt][0]), (short)f2b(acc[mt][nt][1]),
                  (short)f2b(acc[mt][nt][2]), (short)f2b(acc[mt][nt][3])};
        *(bf4*)&Vt[(size_t)((b * 12 + h) * 64 + d) * 2048 + n2] = pk;
      }
    }
    return;
  }
#pragma unroll
  for (int mt = 0; mt < 4; mt++) {
    int row = bm + wr * 64 + mt * 16 + quad * 4;
#pragma unroll
    for (int nt = 0; nt < 4; nt++) {
      int col = bn + wc * 64 + nt * 16 + l16;
      float bv = 0.f;
      if (BIAS)
        bv = f32o ? ((const float*)bias)[col] : b2f(((const u16*)bias)[col]);
#pragma unroll
      for (int r = 0; r < 4; r++) {
        size_t idx = (size_t)(row + r) * Ncols + col;
        float v = acc[mt][nt][r] + bv;
        if (f32o) ((float*)C)[idx] = v; else ((u16*)C)[idx] = f2b(v);
      }
    }
  }
}

// ---------------- flash attention v10 (R13, FROZEN): triple-buffer ---------
// Per buffer: K0|K1|V0|V1, each 64 rows x 32 cols, 64B rows, XOR-swizzled
// (R11). 4 gload16/wave per tile. Raw s_barrier + s_waitcnt vmcnt(4): the
// next tile's DMA stays in flight across the barrier (T3/T4); each tile has
// 2 compute phases to land. Softmax denominator via ones-row MFMA (lacc).
// Fixed-max exp2 softmax (-M0 in MFMA C init); P in B-fragment registers
// (V key-permuted by gemm-QKV epilogue); P packed via v_perm_b32.
__global__ __launch_bounds__(256, 3) void flash_attn(
    const u16* __restrict__ qkv, const u16* __restrict__ Vt,
    u16* __restrict__ O, float* __restrict__ qe, float* __restrict__ lout) {
  __shared__ alignas(16) u16 lds[3][8192];  // 3 x 16 KB
  const int t = threadIdx.x, lane = t & 63, wave = t >> 6;
  const int quad = lane >> 4, l16 = lane & 15;
  const int id = blockIdx.x;
  const int bh = (id & 7) + 8 * (id >> 7);
  const int qtile = (id >> 3) & 15;
  const int b = bh / 12, h = bh - b * 12;
  const int q0 = qtile * 128 + wave * 32;
  const bool dumpP = (qe != nullptr) && (qtile == 0) && (wave == 0);
  const float SCALE2 = 0.125f * 1.44269504089f;
  const float mM0 = -16.f;
  bf8 qf[2][2];
#pragma unroll
  for (int qt = 0; qt < 2; qt++) {
    const u16* Qr = qkv + (size_t)(b * 2048 + q0 + qt * 16 + l16) * 2304 + h * 64;
    bf8 r0 = *(const bf8*)(Qr + quad * 8);
    bf8 r1 = *(const bf8*)(Qr + 32 + quad * 8);
#pragma unroll
    for (int j = 0; j < 8; j++) {
      qf[qt][0][j] = (short)f2b(b2f((u16)r0[j]) * SCALE2);
      qf[qt][1][j] = (short)f2b(b2f((u16)r1[j]) * SCALE2);
    }
  }
  bf8 ones;
#pragma unroll
  for (int j = 0; j < 8; j++) ones[j] = (short)0x3F80;
  const u16* Kb = qkv + (size_t)(b * 2048) * 2304 + 768 + h * 64;
  const u16* Vb = Vt + (size_t)((b * 12 + h) * 64) * 2048;
  const int drow = wave * 16 + (lane >> 2);  // DMA row within 64-row tiles
  // T2: pre-swizzled global source col; LDS dest stays linear (lane*16).
  const int dcol = ((lane & 3) ^ ((lane >> 3) & 3)) * 8;
  // T2: matching read-side col swizzle ((row>>1)&3 == (l16>>1)&3 here).
  const int swz = (quad ^ ((l16 >> 1) & 3)) * 8;
  f4 o[2][4] = {};
  f4 lacc[2] = {};

#define STAGE(tile, buf)                                            \
  {                                                                 \
    int n1_ = (tile) * 64;                                          \
    const u16* Kt_ = Kb + (size_t)(n1_ + drow) * 2304 + dcol;       \
    const u16* Vr_ = Vb + (size_t)drow * 2048 + n1_ + dcol;         \
    u16* base_ = &lds[buf][wave * 512];                             \
    gload16(Kt_, base_);                                            \
    gload16(Kt_ + 32, base_ + 2048);                                \
    gload16(Vr_, base_ + 4096);                                     \
    gload16(Vr_ + 32, base_ + 6144);                                \
  }

  STAGE(0, 0);
  STAGE(1, 1);

  int cur = 0;
  for (int i = 0; i < 32; i++) {
    // tile i's 4 loads retired; tile i+1's 4 stay in flight across barrier
    if (i < 31) {
      asm volatile("s_waitcnt vmcnt(4)" ::: "memory");
    } else {
      asm volatile("s_waitcnt vmcnt(0)" ::: "memory");
    }
    __builtin_amdgcn_s_barrier();
    // prefetch tile i+2 into buf (cur+2)%3 (its last reader finished
    // before the barrier above)
    if (i + 2 < 32) {
      int pre = cur + 2; if (pre >= 3) pre -= 3;
      STAGE(i + 2, pre);
    }
    const u16* K0 = &lds[cur][0];
    const u16* K1 = &lds[cur][2048];
    // S^T (exp2 domain, -M0 pre-folded) -> P in B-fragment registers
    union { i4 i; bf8 b; } pf[2][2];
#pragma unroll
    for (int kt = 0; kt < 4; kt++) {
      bf8 kf0 = *(const bf8*)&K0[(kt * 16 + l16) * 32 + swz];
      bf8 kf1 = *(const bf8*)&K1[(kt * 16 + l16) * 32 + swz];
#pragma unroll
      for (int qt = 0; qt < 2; qt++) {
        f4 z = {mM0, mM0, mM0, mM0};
        z = MFMA16(kf0, qf[qt][0], z);
        z = MFMA16(kf1, qf[qt][1], z);
        float e0 = EXP2(z[0]);
        float e1 = EXP2(z[1]);
        float e2 = EXP2(z[2]);
        float e3 = EXP2(z[3]);
        if (qt == 0 && dumpP && l16 == 0) {
          f4 ev = {e0, e1, e2, e3};
          *(f4*)&qe[bh * 2048 + i * 64 + kt * 16 + quad * 4] = ev;
        }
        pf[qt][kt >> 1].i[(kt & 1) * 2 + 0] = (int)pack2(e0, e1);
        pf[qt][kt >> 1].i[(kt & 1) * 2 + 1] = (int)pack2(e2, e3);
      }
    }
#pragma unroll
    for (int pair = 0; pair < 2; pair++) {
      const u16* Vp = &lds[cur][4096 + pair * 2048];
      lacc[0] = MFMA16(ones, pf[0][pair].b, lacc[0]);
      lacc[1] = MFMA16(ones, pf[1][pair].b, lacc[1]);
#pragma unroll
      for (int nt = 0; nt < 4; nt++) {
        bf8 vf = *(const bf8*)&Vp[(nt * 16 + l16) * 32 + swz];
        o[0][nt] = MFMA16(vf, pf[0][pair].b, o[0][nt]);
        o[1][nt] = MFMA16(vf, pf[1][pair].b, o[1][nt]);
      }
    }
    cur = (cur == 2) ? 0 : cur + 1;
  }
#undef STAGE
#pragma unroll
  for (int qt = 0; qt < 2; qt++) {
    float l = lacc[qt][0];  // every lane: full denom for its q-column
    if (qt == 0 && dumpP && lane == 0) lout[bh] = l;
    float inv = 1.f / l;
    size_t row = (size_t)(b * 2048 + q0 + qt * 16 + l16) * 768 + h * 64;
#pragma unroll
    for (int nt = 0; nt < 4; nt++) {
      bf4 pk = {(short)f2b(o[qt][nt][0] * inv), (short)f2b(o[qt][nt][1] * inv),
                (short)f2b(o[qt][nt][2] * inv), (short)f2b(o[qt][nt][3] * inv)};
      *(bf4*)&O[row + nt * 16 + quad * 4] = pk;
    }
  }
}

// ---------------- fallback q_attn (if workspace too small) -----------------
__global__ __launch_bounds__(256) void qattn_row0(
    const u16* __restrict__ qkv, void* __restrict__ out,
    const u16* __restrict__ xdet) {
  const int bh = blockIdx.x, b = bh / 12, h = bh % 12;
  __shared__ float qs[64];
  __shared__ float sv[2048];
  __shared__ float red[8];
  const int t = threadIdx.x;
  const int f32o = detect_f32(xdet);
  if (t < 64) qs[t] = b2f(qkv[(size_t)(b * 2048) * 2304 + h * 64 + t]);
  __syncthreads();
  float lmax = -1e30f;
  for (int k = t; k < 2048; k += 256) {
    const u16* Kr = qkv + (size_t)(b * 2048 + k) * 2304 + 768 + h * 64;
    float acc = 0.f;
#pragma unroll
    for (int j = 0; j < 8; j++) {
      bf8 kv = *(const bf8*)(Kr + j * 8);
#pragma unroll
      for (int d = 0; d < 8; d++) acc += qs[j * 8 + d] * b2f((u16)kv[d]);
    }
    acc *= 0.125f;
    sv[k] = acc;
    lmax = fmaxf(lmax, acc);
  }
#pragma unroll
  for (int off = 32; off >= 1; off >>= 1) lmax = fmaxf(lmax, __shfl_xor(lmax, off, 64));
  if ((t & 63) == 0) red[t >> 6] = lmax;
  __syncthreads();
  const float bmax = fmaxf(fmaxf(red[0], red[1]), fmaxf(red[2], red[3]));
  float lsum = 0.f;
  for (int k = t; k < 2048; k += 256) {
    float e = __expf(sv[k] - bmax);
    sv[k] = e;
    lsum += e;
  }
#pragma unroll
  for (int off = 32; off >= 1; off >>= 1) lsum += __shfl_xor(lsum, off, 64);
  if ((t & 63) == 0) red[4 + (t >> 6)] = lsum;
  __syncthreads();
  const float inv = 1.f / (red[4] + red[5] + red[6] + red[7]);
  for (int k = t; k < 2048; k += 256) {
    size_t idx = (size_t)6291456 + (size_t)bh * 2048 + k;
    float v = sv[k] * inv;
    if (f32o) ((float*)out)[idx] = v; else ((u16*)out)[idx] = f2b(v);
  }
}

extern "C" void kernel_launch(void* const* d_in, const int* in_sizes, int n_in,
                              void* d_out, int out_size, void* d_ws, size_t ws_size,
                              hipStream_t stream) {
  const void* x_raw      = d_in[0];
  const void* w_qkv_raw  = d_in[1];
  const void* w_proj_raw = d_in[2];
  const void* b_proj_raw = d_in[3];
  const u16* xdet = (const u16*)x_raw;
  char* ws = (char*)d_ws;
  u16* xbf    = (u16*)(ws + 256);            // 12,582,912 B (aliased by attn later)
  u16* wqkvT  = (u16*)(ws + 12583168);       //  3,538,944 B
  u16* wprojT = (u16*)(ws + 16122112);       //  1,179,648 B
  u16* qkv    = (u16*)(ws + 17301760);       // 37,748,736 B (V region unused)
  u16* Vt     = (u16*)(ws + 55050496);       // 12,582,912 B -> 67,633,408
  float* qe   = (float*)(ws + 67633408);     //    393,216 B
  float* lout = (float*)(ws + 68026624);     //        192 B -> 68,026,816
  u16* attn   = xbf;
  const bool fused = ws_size >= 68026816ull;

  prep<<<dim3(72, 24, 3), 256, 0, stream>>>(
      x_raw, xbf, w_qkv_raw, wqkvT, w_proj_raw, wprojT);
  gemm_qkv8<<<dim3(8, 64), 512, 0, stream>>>(xbf, wqkvT, qkv, Vt);
  flash_attn<<<dim3(768), 256, 0, stream>>>(qkv, Vt, attn,
                                            fused ? qe : nullptr,
                                            fused ? lout : nullptr);
  if (fused) {
    gemm_proj4<<<dim3(7, 128), 256, 0, stream>>>(
        attn, wprojT, b_proj_raw, d_out, xdet, qe, lout);
  } else {
    gemm_bt<1, 0><<<dim3(6, 64), 256, 0, stream>>>(
        attn, wprojT, b_proj_raw, d_out, 8192, 768, 768, xdet, nullptr, nullptr, nullptr);
    qattn_row0<<<dim3(48), 256, 0, stream>>>(qkv, d_out, xdet);
  }
}